// Round 4
// baseline (836.583 us; speedup 1.0000x reference)
//
#include <hip/hip_runtime.h>

#define NWG   512
#define NTHR  256
#define F     59
#define K0    29
#define NB    15
#define BROWS 131072
#define LSTR  61   // LDS row stride, gcd(61,32)=1 -> conflict-free columns
#define NSLC  8    // sliced fp64 accumulators: one 64B line per (feature,slice)

// d_ws layout (doubles): acc[NB][F][NSLC][8]  then scsh[NB][128]
#define ACC_PER_LAYER (F * NSLC * 8)            // 3776 doubles / layer
#define ACC_TOTAL     (NB * ACC_PER_LAYER)      // 56640 doubles = 453120 B

// ---------------------------------------------------------------------------
// One Linear+ReLU layer. Row-per-thread. Reads its own input row fully into
// registers (in-place safe; `in`/`hout` intentionally NOT __restrict__ since
// they alias), normalizes with the previous layer's scale/shift on the fly,
// does the 59-wide dot in fp64, writes post-ReLU h (f32) to d_out and LDS,
// then per-block fp64 column sums -> sliced global fp64 atomics.
// No cross-block synchronization of any kind.
// ---------------------------------------------------------------------------
template<int K, bool FIRST>
__global__ void __launch_bounds__(NTHR)
layer_kernel(const float* in, const float* __restrict__ W,
             const float* __restrict__ bvec,
             const double* __restrict__ scsh_in,   // ignored when FIRST
             float* hout, double* acc)
{
  __shared__ float  ybuf[NTHR * LSTR];   // 62464 B
  __shared__ double part_s[256];         //  2048 B
  __shared__ double part_ss[256];        //  2048 B

  const int tid   = threadIdx.x;
  const int row   = blockIdx.x * NTHR + tid;
  const int slice = blockIdx.x & (NSLC - 1);

  // ---- load (and normalize) own input row into registers, fp64 ----
  double hin[K];
  const float* ir = in + (size_t)row * K;
  if (FIRST) {
    #pragma unroll
    for (int k = 0; k < K; ++k) hin[k] = (double)ir[k];
  } else {
    #pragma unroll
    for (int k = 0; k < K; ++k)
      hin[k] = fma((double)ir[k], scsh_in[k], scsh_in[64 + k]);
  }

  // ---- Linear + ReLU, fp64 accumulate ----
  float* yrow = ybuf + tid * LSTR;
  float* orow = hout + (size_t)row * F;
  #pragma unroll 2
  for (int j = 0; j < F; ++j) {
    const float* wp = W + j * K;        // uniform across lanes -> scalar loads
    double a = (double)bvec[j];
    #pragma unroll
    for (int k = 0; k < K; ++k) a = fma(hin[k], (double)wp[k], a);
    a = fmax(a, 0.0);
    float hf = (float)a;
    yrow[j] = hf;
    orow[j] = hf;                        // h stored f32 (matches f32 pipeline)
  }
  __syncthreads();

  // ---- per-block column sums (fp64) over the f32 h values ----
  if (tid < 4 * F) {                     // 236 active: feature j, row-chunk c
    int j = tid % F, c = tid / F;
    double s1 = 0.0, s2 = 0.0;
    const float* col = ybuf + (c * 64) * LSTR + j;
    #pragma unroll
    for (int i = 0; i < 64; ++i) {
      double v = (double)col[i * LSTR];
      s1 += v;
      s2 = fma(v, v, s2);
    }
    part_s[c * 64 + j]  = s1;
    part_ss[c * 64 + j] = s2;
  }
  __syncthreads();

  if (tid < F) {
    double t1 = part_s[tid] + part_s[64 + tid] + part_s[128 + tid] + part_s[192 + tid];
    double t2 = part_ss[tid] + part_ss[64 + tid] + part_ss[128 + tid] + part_ss[192 + tid];
    double* slot = acc + (size_t)(tid * NSLC + slice) * 8;
    atomicAdd(slot,     t1);             // hw f64 atomic, device scope
    atomicAdd(slot + 1, t2);
  }
}

// ---------------------------------------------------------------------------
// Finalize one layer's stats -> scale/shift (runs after layer_kernel by
// stream order; kernel-boundary coherence, no fences needed).
// ---------------------------------------------------------------------------
__global__ void stats_kernel(const double* __restrict__ acc,
                             const float* __restrict__ g,
                             const float* __restrict__ bt,
                             double* __restrict__ scsh_out)
{
  int j = threadIdx.x;
  if (j >= F) return;
  double s1 = 0.0, s2 = 0.0;
  #pragma unroll
  for (int s = 0; s < NSLC; ++s) {
    const double* slot = acc + (size_t)(j * NSLC + s) * 8;
    s1 += slot[0];
    s2 += slot[1];
  }
  const double inv = 1.0 / (double)BROWS;
  double mu   = s1 * inv;
  double var  = fma(s2, inv, -mu * mu);       // biased variance, fp64
  double rstd = 1.0 / sqrt(var + 1e-5);
  double sc   = rstd * (double)g[j];
  scsh_out[j]      = sc;
  scsh_out[64 + j] = fma(-mu, sc, (double)bt[j]);
}

// ---------------------------------------------------------------------------
// Apply the last layer's normalization in place.
// ---------------------------------------------------------------------------
__global__ void __launch_bounds__(NTHR)
final_kernel(float* h, const double* __restrict__ scsh)
{
  const int row = blockIdx.x * NTHR + threadIdx.x;
  float* hr = h + (size_t)row * F;
  #pragma unroll
  for (int j = 0; j < F; ++j)
    hr[j] = (float)fma((double)hr[j], scsh[j], scsh[64 + j]);
}

// ---------------------------------------------------------------------------
extern "C" void kernel_launch(void* const* d_in, const int* in_sizes, int n_in,
                              void* d_out, int out_size, void* d_ws, size_t ws_size,
                              hipStream_t stream)
{
  const float* x   = (const float*)d_in[0];
  const float* W0  = (const float*)d_in[1];
  const float* b0  = (const float*)d_in[2];
  const float* g0  = (const float*)d_in[3];
  const float* bt0 = (const float*)d_in[4];
  const float* Ws  = (const float*)d_in[5];
  const float* bs  = (const float*)d_in[6];
  const float* gs  = (const float*)d_in[7];
  const float* bts = (const float*)d_in[8];
  float* out = (float*)d_out;

  double* acc  = (double*)d_ws;               // [NB][F][NSLC][8]
  double* scsh = acc + ACC_TOTAL;             // [NB][128]

  // zero the atomic accumulators every call (deterministic, capture-safe)
  hipMemsetAsync(d_ws, 0, (size_t)ACC_TOTAL * sizeof(double), stream);

  // layer 0: x[B,29] -> h in d_out
  layer_kernel<K0, true><<<NWG, NTHR, 0, stream>>>(x, W0, b0, scsh, out, acc);
  stats_kernel<<<1, 64, 0, stream>>>(acc, g0, bt0, scsh);

  // layers 1..14: in-place on d_out, normalizing previous layer on read
  for (int b = 1; b < NB; ++b) {
    layer_kernel<F, false><<<NWG, NTHR, 0, stream>>>(
        out, Ws + (size_t)(b - 1) * F * F, bs + (size_t)(b - 1) * F,
        scsh + (size_t)(b - 1) * 128, out, acc + (size_t)b * ACC_PER_LAYER);
    stats_kernel<<<1, 64, 0, stream>>>(acc + (size_t)b * ACC_PER_LAYER,
                                       gs + (size_t)(b - 1) * F,
                                       bts + (size_t)(b - 1) * F,
                                       scsh + (size_t)b * 128);
  }

  // apply last layer's BN in place
  final_kernel<<<NWG, NTHR, 0, stream>>>(out, scsh + (size_t)(NB - 1) * 128);
}

// Round 5
// 726.411 us; speedup vs baseline: 1.1517x; 1.1517x over previous
//
#include <hip/hip_runtime.h>

#define NWG   512
#define NTHR  256
#define F     59
#define K0    29
#define NB    15
#define BROWS 131072
#define LSTR  61   // LDS row stride, gcd(61,32)=1 -> conflict-free columns
#define NSLC  8    // sliced fp64 accumulators: one 64B line per (feature,slice)

// d_ws layout (doubles): acc[NB][F][NSLC][8]
#define ACC_PER_LAYER (F * NSLC * 8)            // 3776 doubles / layer
#define ACC_TOTAL     (NB * ACC_PER_LAYER)      // 56640 doubles = 453120 B

// ---------------------------------------------------------------------------
// Finalize previous layer's stats (fp64) into LDS scale/shift (f32).
// Runs redundantly in every block; acc_prev is complete by stream order.
// ---------------------------------------------------------------------------
__device__ __forceinline__ void make_scsh(const double* __restrict__ acc_prev,
                                          const float* __restrict__ g,
                                          const float* __restrict__ bt,
                                          float* scsh, int tid)
{
  if (tid < F) {
    double s1 = 0.0, s2 = 0.0;
    #pragma unroll
    for (int s = 0; s < NSLC; ++s) {
      const double* slot = acc_prev + (size_t)(tid * NSLC + s) * 8;
      s1 += slot[0];
      s2 += slot[1];
    }
    const double inv = 1.0 / (double)BROWS;
    double mu   = s1 * inv;
    double var  = fma(s2, inv, -mu * mu);        // biased variance, fp64
    double rstd = 1.0 / sqrt(var + 1e-5);
    double sc   = rstd * (double)g[tid];
    scsh[tid]      = (float)sc;
    scsh[64 + tid] = (float)fma(-mu, sc, (double)bt[tid]);
  }
  __syncthreads();
}

// ---------------------------------------------------------------------------
// One Linear+ReLU layer, fp32 value path. Row-per-thread, in-place on d_out
// (`in`/`hout` alias: each thread reads its whole row into registers first).
// If !FIRST, normalizes the input row with the previous layer's scale/shift.
// Post-ReLU y -> global + LDS; fp64 column sums -> sliced f64 atomics.
// ---------------------------------------------------------------------------
template<int K, bool FIRST>
__global__ void __launch_bounds__(NTHR)
layer_kernel(const float* in, const float* __restrict__ W,
             const float* __restrict__ bvec,
             const double* __restrict__ acc_prev,    // prev layer stats (unless FIRST)
             const float* __restrict__ g_prev, const float* __restrict__ bt_prev,
             float* hout, double* acc)
{
  __shared__ float  ybuf[NTHR * LSTR];   // 62464 B
  __shared__ double part_s[256];         //  2048 B
  __shared__ double part_ss[256];        //  2048 B
  __shared__ float  scsh[128];           //   512 B

  const int tid   = threadIdx.x;
  const int row   = blockIdx.x * NTHR + tid;
  const int slice = blockIdx.x & (NSLC - 1);

  if (!FIRST) make_scsh(acc_prev, g_prev, bt_prev, scsh, tid);

  // ---- load (and normalize) own input row into registers, fp32 ----
  float h[K];
  const float* ir = in + (size_t)row * K;
  #pragma unroll
  for (int k = 0; k < K; ++k) {
    float v = ir[k];
    h[k] = FIRST ? v : fmaf(v, scsh[k], scsh[64 + k]);
  }

  // ---- Linear + ReLU (fp32, 4-wide ILP, scalar weight loads) ----
  float* yrow = ybuf + tid * LSTR;
  float* orow = hout + (size_t)row * F;
  #pragma unroll 2
  for (int j0 = 0; j0 + 4 <= F; j0 += 4) {
    const float* wp = W + j0 * K;
    float a0 = bvec[j0], a1 = bvec[j0 + 1], a2 = bvec[j0 + 2], a3 = bvec[j0 + 3];
    #pragma unroll
    for (int k = 0; k < K; ++k) {
      float hk = h[k];
      a0 = fmaf(hk, wp[k],         a0);
      a1 = fmaf(hk, wp[K + k],     a1);
      a2 = fmaf(hk, wp[2 * K + k], a2);
      a3 = fmaf(hk, wp[3 * K + k], a3);
    }
    a0 = fmaxf(a0, 0.f); a1 = fmaxf(a1, 0.f);
    a2 = fmaxf(a2, 0.f); a3 = fmaxf(a3, 0.f);
    yrow[j0] = a0; yrow[j0 + 1] = a1; yrow[j0 + 2] = a2; yrow[j0 + 3] = a3;
    orow[j0] = a0; orow[j0 + 1] = a1; orow[j0 + 2] = a2; orow[j0 + 3] = a3;
  }
  { // tail j = 56..58
    const float* wp = W + 56 * K;
    float a0 = bvec[56], a1 = bvec[57], a2 = bvec[58];
    #pragma unroll
    for (int k = 0; k < K; ++k) {
      float hk = h[k];
      a0 = fmaf(hk, wp[k],         a0);
      a1 = fmaf(hk, wp[K + k],     a1);
      a2 = fmaf(hk, wp[2 * K + k], a2);
    }
    a0 = fmaxf(a0, 0.f); a1 = fmaxf(a1, 0.f); a2 = fmaxf(a2, 0.f);
    yrow[56] = a0; yrow[57] = a1; yrow[58] = a2;
    orow[56] = a0; orow[57] = a1; orow[58] = a2;
  }
  __syncthreads();

  // ---- per-block column sums (fp64) over the f32 y values ----
  if (tid < 4 * F) {                     // 236 active: feature j, row-chunk c
    int j = tid % F, c = tid / F;
    double s1 = 0.0, s2 = 0.0;
    const float* col = ybuf + (c * 64) * LSTR + j;
    #pragma unroll
    for (int i = 0; i < 64; ++i) {
      double v = (double)col[i * LSTR];
      s1 += v;
      s2 = fma(v, v, s2);
    }
    part_s[c * 64 + j]  = s1;
    part_ss[c * 64 + j] = s2;
  }
  __syncthreads();

  if (tid < F) {
    double t1 = part_s[tid] + part_s[64 + tid] + part_s[128 + tid] + part_s[192 + tid];
    double t2 = part_ss[tid] + part_ss[64 + tid] + part_ss[128 + tid] + part_ss[192 + tid];
    double* slot = acc + (size_t)(tid * NSLC + slice) * 8;
    atomicAdd(slot,     t1);             // hw f64 atomic, device scope
    atomicAdd(slot + 1, t2);
  }
}

// ---------------------------------------------------------------------------
// Apply the last layer's BN in place (computes scsh redundantly per block).
// ---------------------------------------------------------------------------
__global__ void __launch_bounds__(NTHR)
final_kernel(float* h, const double* __restrict__ acc_last,
             const float* __restrict__ g, const float* __restrict__ bt)
{
  __shared__ float scsh[128];
  const int tid = threadIdx.x;
  make_scsh(acc_last, g, bt, scsh, tid);

  const int row = blockIdx.x * NTHR + tid;
  float* hr = h + (size_t)row * F;
  float v[F];
  #pragma unroll
  for (int j = 0; j < F; ++j) v[j] = fmaf(hr[j], scsh[j], scsh[64 + j]);
  #pragma unroll
  for (int j = 0; j < F; ++j) hr[j] = v[j];
}

// ---------------------------------------------------------------------------
extern "C" void kernel_launch(void* const* d_in, const int* in_sizes, int n_in,
                              void* d_out, int out_size, void* d_ws, size_t ws_size,
                              hipStream_t stream)
{
  const float* x   = (const float*)d_in[0];
  const float* W0  = (const float*)d_in[1];
  const float* b0  = (const float*)d_in[2];
  const float* g0  = (const float*)d_in[3];
  const float* bt0 = (const float*)d_in[4];
  const float* Ws  = (const float*)d_in[5];
  const float* bs  = (const float*)d_in[6];
  const float* gs  = (const float*)d_in[7];
  const float* bts = (const float*)d_in[8];
  float* out = (float*)d_out;

  double* acc = (double*)d_ws;               // [NB][F][NSLC][8]

  // zero the atomic accumulators every call (deterministic, capture-safe)
  hipMemsetAsync(d_ws, 0, (size_t)ACC_TOTAL * sizeof(double), stream);

  // layer 0: x[B,29] -> y0 in d_out (no input normalization)
  layer_kernel<K0, true><<<NWG, NTHR, 0, stream>>>(
      x, W0, b0, nullptr, nullptr, nullptr, out, acc);

  // layers 1..14: in-place on d_out, normalizing previous layer on read;
  // previous layer's stats finalized redundantly inside each block.
  for (int b = 1; b < NB; ++b) {
    const float* gp  = (b == 1) ? g0  : gs  + (size_t)(b - 2) * F;
    const float* btp = (b == 1) ? bt0 : bts + (size_t)(b - 2) * F;
    layer_kernel<F, false><<<NWG, NTHR, 0, stream>>>(
        out, Ws + (size_t)(b - 1) * F * F, bs + (size_t)(b - 1) * F,
        acc + (size_t)(b - 1) * ACC_PER_LAYER, gp, btp,
        out, acc + (size_t)b * ACC_PER_LAYER);
  }

  // apply layer 14's BN in place
  final_kernel<<<NWG, NTHR, 0, stream>>>(
      out, acc + (size_t)(NB - 1) * ACC_PER_LAYER,
      gs + (size_t)(NB - 2) * F, bts + (size_t)(NB - 2) * F);
}

// Round 6
// 670.421 us; speedup vs baseline: 1.2478x; 1.0835x over previous
//
#include <hip/hip_runtime.h>

#define NWG   512
#define NTHR  256
#define F     59
#define K0    29
#define NB    15
#define BROWS 131072
#define LSTR  61   // LDS row stride, gcd(61,32)=1 -> conflict-free columns
#define NSLC  8    // sliced fp64 accumulators: one 64B line per (feature,slice)

// d_ws layout: acc[NB][F][NSLC][8] doubles, then hT[F][BROWS] floats
#define ACC_PER_LAYER (F * NSLC * 8)            // 3776 doubles / layer
#define ACC_TOTAL     (NB * ACC_PER_LAYER)      // 56640 doubles = 453120 B
#define HT_OFF_B      ((size_t)ACC_TOTAL * 8)
#define WS_NEEDED     (HT_OFF_B + (size_t)F * BROWS * 4)

// ---------------------------------------------------------------------------
// Finalize previous layer's stats (fp64) into LDS scale/shift (f32).
// Runs redundantly in every block; acc_prev is complete by stream order.
// ---------------------------------------------------------------------------
__device__ __forceinline__ void make_scsh(const double* __restrict__ acc_prev,
                                          const float* __restrict__ g,
                                          const float* __restrict__ bt,
                                          float* scsh, int tid)
{
  if (tid < F) {
    double s1 = 0.0, s2 = 0.0;
    #pragma unroll
    for (int s = 0; s < NSLC; ++s) {
      const double* slot = acc_prev + (size_t)(tid * NSLC + s) * 8;
      s1 += slot[0];
      s2 += slot[1];
    }
    const double inv = 1.0 / (double)BROWS;
    double mu   = s1 * inv;
    double var  = fma(s2, inv, -mu * mu);        // biased variance, fp64
    double rstd = 1.0 / sqrt(var + 1e-5);
    double sc   = rstd * (double)g[tid];
    scsh[tid]      = (float)sc;
    scsh[64 + tid] = (float)fma(-mu, sc, (double)bt[tid]);
  }
  __syncthreads();
}

// ---------------------------------------------------------------------------
// One Linear+ReLU layer, fp32 value path, row-per-thread.
// TRIN/TROUT select transposed [F][B] (coalesced) vs row-major [B][F] h.
// In-place safe (each thread reads its whole row into regs before writing).
// Post-ReLU y -> global + LDS; fp64 column sums -> sliced f64 atomics.
// ---------------------------------------------------------------------------
template<int K, bool FIRST, bool TRIN, bool TROUT>
__global__ void __launch_bounds__(NTHR)
layer_kernel(const float* in, const float* __restrict__ W,
             const float* __restrict__ bvec,
             const double* __restrict__ acc_prev,    // prev layer stats (unless FIRST)
             const float* __restrict__ g_prev, const float* __restrict__ bt_prev,
             float* hout, double* acc)
{
  __shared__ float  ybuf[NTHR * LSTR];   // 62464 B
  __shared__ double part_s[256];         //  2048 B
  __shared__ double part_ss[256];        //  2048 B
  __shared__ float  scsh[128];           //   512 B

  const int tid   = threadIdx.x;
  const int row   = blockIdx.x * NTHR + tid;
  const int slice = blockIdx.x & (NSLC - 1);

  if (!FIRST) make_scsh(acc_prev, g_prev, bt_prev, scsh, tid);

  // ---- load (and normalize) own input row into registers, fp32 ----
  float h[K];
  if (FIRST) {
    // stage x block through LDS: coalesced global, conflict-free LDS (K odd)
    const float* xblk = in + (size_t)blockIdx.x * NTHR * K;
    #pragma unroll 4
    for (int i = tid; i < NTHR * K; i += NTHR) ybuf[i] = xblk[i];
    __syncthreads();
    #pragma unroll
    for (int k = 0; k < K; ++k) h[k] = ybuf[tid * K + k];
    __syncthreads();   // ybuf reused for y below
  } else if (TRIN) {
    #pragma unroll
    for (int k = 0; k < K; ++k)
      h[k] = fmaf(in[(size_t)k * BROWS + row], scsh[k], scsh[64 + k]);
  } else {
    const float* ir = in + (size_t)row * K;
    #pragma unroll
    for (int k = 0; k < K; ++k) h[k] = fmaf(ir[k], scsh[k], scsh[64 + k]);
  }

  // ---- Linear + ReLU (fp32, 4-wide ILP, scalar weight loads) ----
  float* yrow = ybuf + tid * LSTR;
  float* orow = TROUT ? hout + row : hout + (size_t)row * F;
  #pragma unroll 2
  for (int j0 = 0; j0 + 4 <= F; j0 += 4) {
    const float* wp = W + j0 * K;
    float a0 = bvec[j0], a1 = bvec[j0 + 1], a2 = bvec[j0 + 2], a3 = bvec[j0 + 3];
    #pragma unroll
    for (int k = 0; k < K; ++k) {
      float hk = h[k];
      a0 = fmaf(hk, wp[k],         a0);
      a1 = fmaf(hk, wp[K + k],     a1);
      a2 = fmaf(hk, wp[2 * K + k], a2);
      a3 = fmaf(hk, wp[3 * K + k], a3);
    }
    a0 = fmaxf(a0, 0.f); a1 = fmaxf(a1, 0.f);
    a2 = fmaxf(a2, 0.f); a3 = fmaxf(a3, 0.f);
    yrow[j0] = a0; yrow[j0 + 1] = a1; yrow[j0 + 2] = a2; yrow[j0 + 3] = a3;
    if (TROUT) {
      orow[(size_t)j0 * BROWS]       = a0;   // lane-consecutive: coalesced
      orow[(size_t)(j0 + 1) * BROWS] = a1;
      orow[(size_t)(j0 + 2) * BROWS] = a2;
      orow[(size_t)(j0 + 3) * BROWS] = a3;
    } else {
      orow[j0] = a0; orow[j0 + 1] = a1; orow[j0 + 2] = a2; orow[j0 + 3] = a3;
    }
  }
  { // tail j = 56..58
    const float* wp = W + 56 * K;
    float a0 = bvec[56], a1 = bvec[57], a2 = bvec[58];
    #pragma unroll
    for (int k = 0; k < K; ++k) {
      float hk = h[k];
      a0 = fmaf(hk, wp[k],         a0);
      a1 = fmaf(hk, wp[K + k],     a1);
      a2 = fmaf(hk, wp[2 * K + k], a2);
    }
    a0 = fmaxf(a0, 0.f); a1 = fmaxf(a1, 0.f); a2 = fmaxf(a2, 0.f);
    yrow[56] = a0; yrow[57] = a1; yrow[58] = a2;
    if (TROUT) {
      orow[(size_t)56 * BROWS] = a0;
      orow[(size_t)57 * BROWS] = a1;
      orow[(size_t)58 * BROWS] = a2;
    } else {
      orow[56] = a0; orow[57] = a1; orow[58] = a2;
    }
  }
  __syncthreads();

  // ---- per-block column sums (fp64) over the f32 y values ----
  if (tid < 4 * F) {                     // 236 active: feature j, row-chunk c
    int j = tid % F, c = tid / F;
    double s1 = 0.0, s2 = 0.0;
    const float* col = ybuf + (c * 64) * LSTR + j;
    #pragma unroll
    for (int i = 0; i < 64; ++i) {
      double v = (double)col[i * LSTR];
      s1 += v;
      s2 = fma(v, v, s2);
    }
    part_s[c * 64 + j]  = s1;
    part_ss[c * 64 + j] = s2;
  }
  __syncthreads();

  if (tid < F) {
    double t1 = part_s[tid] + part_s[64 + tid] + part_s[128 + tid] + part_s[192 + tid];
    double t2 = part_ss[tid] + part_ss[64 + tid] + part_ss[128 + tid] + part_ss[192 + tid];
    double* slot = acc + (size_t)(tid * NSLC + slice) * 8;
    atomicAdd(slot,     t1);             // hw f64 atomic, device scope
    atomicAdd(slot + 1, t2);
  }
}

// ---------------------------------------------------------------------------
// Final BN from transposed hT -> row-major out (coalesced both sides via LDS).
// ---------------------------------------------------------------------------
__global__ void __launch_bounds__(NTHR)
final_tr_kernel(const float* __restrict__ hT, const double* __restrict__ acc_last,
                const float* __restrict__ g, const float* __restrict__ bt,
                float* __restrict__ out)
{
  __shared__ float ybuf[NTHR * LSTR];
  __shared__ float scsh[128];
  const int tid = threadIdx.x;
  make_scsh(acc_last, g, bt, scsh, tid);

  const int row = blockIdx.x * NTHR + tid;
  #pragma unroll
  for (int j = 0; j < F; ++j)
    ybuf[tid * LSTR + j] = fmaf(hT[(size_t)j * BROWS + row], scsh[j], scsh[64 + j]);
  __syncthreads();

  float* oblk = out + (size_t)blockIdx.x * NTHR * F;
  #pragma unroll 4
  for (int i = tid; i < NTHR * F; i += NTHR)
    oblk[i] = ybuf[(i / F) * LSTR + (i % F)];
}

// ---------------------------------------------------------------------------
// Fallback final (row-major in place), used when ws too small for hT.
// ---------------------------------------------------------------------------
__global__ void __launch_bounds__(NTHR)
final_kernel(float* h, const double* __restrict__ acc_last,
             const float* __restrict__ g, const float* __restrict__ bt)
{
  __shared__ float scsh[128];
  const int tid = threadIdx.x;
  make_scsh(acc_last, g, bt, scsh, tid);

  const int row = blockIdx.x * NTHR + tid;
  float* hr = h + (size_t)row * F;
  float v[F];
  #pragma unroll
  for (int j = 0; j < F; ++j) v[j] = fmaf(hr[j], scsh[j], scsh[64 + j]);
  #pragma unroll
  for (int j = 0; j < F; ++j) hr[j] = v[j];
}

// ---------------------------------------------------------------------------
extern "C" void kernel_launch(void* const* d_in, const int* in_sizes, int n_in,
                              void* d_out, int out_size, void* d_ws, size_t ws_size,
                              hipStream_t stream)
{
  const float* x   = (const float*)d_in[0];
  const float* W0  = (const float*)d_in[1];
  const float* b0  = (const float*)d_in[2];
  const float* g0  = (const float*)d_in[3];
  const float* bt0 = (const float*)d_in[4];
  const float* Ws  = (const float*)d_in[5];
  const float* bs  = (const float*)d_in[6];
  const float* gs  = (const float*)d_in[7];
  const float* bts = (const float*)d_in[8];
  float* out = (float*)d_out;

  double* acc = (double*)d_ws;               // [NB][F][NSLC][8]
  float*  hT  = (float*)((char*)d_ws + HT_OFF_B);
  const bool tr = (ws_size >= WS_NEEDED);

  // zero the atomic accumulators every call (deterministic, capture-safe)
  hipMemsetAsync(d_ws, 0, (size_t)ACC_TOTAL * sizeof(double), stream);

  if (tr) {
    // layer 0: x[B,29] -> hT[59][B]
    layer_kernel<K0, true, false, true><<<NWG, NTHR, 0, stream>>>(
        x, W0, b0, nullptr, nullptr, nullptr, hT, acc);
    // layers 1..14: in-place transposed, normalize-prev-on-read
    for (int b = 1; b < NB; ++b) {
      const float* gp  = (b == 1) ? g0  : gs  + (size_t)(b - 2) * F;
      const float* btp = (b == 1) ? bt0 : bts + (size_t)(b - 2) * F;
      layer_kernel<F, false, true, true><<<NWG, NTHR, 0, stream>>>(
          hT, Ws + (size_t)(b - 1) * F * F, bs + (size_t)(b - 1) * F,
          acc + (size_t)(b - 1) * ACC_PER_LAYER, gp, btp,
          hT, acc + (size_t)b * ACC_PER_LAYER);
    }
    final_tr_kernel<<<NWG, NTHR, 0, stream>>>(
        hT, acc + (size_t)(NB - 1) * ACC_PER_LAYER,
        gs + (size_t)(NB - 2) * F, bts + (size_t)(NB - 2) * F, out);
  } else {
    // fallback: row-major in d_out (round-5 proven path)
    layer_kernel<K0, true, false, false><<<NWG, NTHR, 0, stream>>>(
        x, W0, b0, nullptr, nullptr, nullptr, out, acc);
    for (int b = 1; b < NB; ++b) {
      const float* gp  = (b == 1) ? g0  : gs  + (size_t)(b - 2) * F;
      const float* btp = (b == 1) ? bt0 : bts + (size_t)(b - 2) * F;
      layer_kernel<F, false, false, false><<<NWG, NTHR, 0, stream>>>(
          out, Ws + (size_t)(b - 1) * F * F, bs + (size_t)(b - 1) * F,
          acc + (size_t)(b - 1) * ACC_PER_LAYER, gp, btp,
          out, acc + (size_t)b * ACC_PER_LAYER);
    }
    final_kernel<<<NWG, NTHR, 0, stream>>>(
        out, acc + (size_t)(NB - 1) * ACC_PER_LAYER,
        gs + (size_t)(NB - 2) * F, bts + (size_t)(NB - 2) * F);
  }
}